// Round 1
// baseline (911.545 us; speedup 1.0000x reference)
//
#include <hip/hip_runtime.h>
#include <stdint.h>

// Problem constants
#define BB   8
#define NH   8
#define QQ   100
#define HWK  16384
#define DM   256
#define HD   32
#define QP   112      // Q padded to 7 * 16
#define MT   7        // m-tiles of 16 rows
#define NPART 64      // key partials per (b,h): 16 chunks * 4 waves
// 1/sqrt(32) * log2(e)  (exp(x) == exp2(x*log2e), folded into q-scale)
#define SCALE2 0.2550602534365564f

typedef short bf16x8 __attribute__((ext_vector_type(8)));
typedef float f32x4  __attribute__((ext_vector_type(4)));
typedef unsigned short u16;
typedef unsigned int   u32;
typedef unsigned long long u64;

__device__ __forceinline__ u16 f2bf(float f) {          // RNE
  u32 u = __builtin_bit_cast(u32, f);
  u += 0x7fffu + ((u >> 16) & 1u);
  return (u16)(u >> 16);
}
__device__ __forceinline__ u16 f2bf_ru(float f) {       // round-half-up (2 VALU)
  return (u16)((__builtin_bit_cast(u32, f) + 0x8000u) >> 16);
}
// pack two fp32 -> bf16x2 (round-half-up), 3 VALU via v_perm
__device__ __forceinline__ u32 pack2rn(float lo, float hi) {
  u32 a = __builtin_bit_cast(u32, lo) + 0x8000u;
  u32 b = __builtin_bit_cast(u32, hi) + 0x8000u;
  return __builtin_amdgcn_perm(b, a, 0x07060302u);
}
__device__ __forceinline__ float bf_lo(u32 u) {
  return __builtin_bit_cast(float, u << 16);
}
__device__ __forceinline__ float bf_hi(u32 u) {
  return __builtin_bit_cast(float, u & 0xffff0000u);
}
__device__ __forceinline__ float fast_exp2(float x) {
#if __has_builtin(__builtin_amdgcn_exp2f)
  return __builtin_amdgcn_exp2f(x);
#else
  return exp2f(x);
#endif
}

// ---------------------------------------------------------------------------
// Kernel 0: convert W_kv (in_proj rows 256..767) fp32 -> bf16, row-major.
// ---------------------------------------------------------------------------
__global__ __launch_bounds__(256) void wconv_kernel(
    const float* __restrict__ W, u16* __restrict__ wbf) {
  const int i = (blockIdx.x * 256 + threadIdx.x) * 4;   // 131072 elems
  const float4 w = *(const float4*)(W + 256 * DM + i);
  u32* dst = (u32*)(wbf + i);
  dst[0] = pack2rn(w.x, w.y);
  dst[1] = pack2rn(w.z, w.w);
}

// ---------------------------------------------------------------------------
// Kernel 1: q projection (scale*log2e folded in).  q_bf layout (b,h,qi,d).
// ---------------------------------------------------------------------------
__global__ __launch_bounds__(256) void proj_q_kernel(
    const float* __restrict__ query, const float* __restrict__ W,
    const float* __restrict__ bias, u16* __restrict__ q_bf) {
  __shared__ float xrow[DM];
  const int bq = blockIdx.x;
  const int b = bq / QQ, qi = bq % QQ;
  const int tid = threadIdx.x;
  if (tid < 64)
    ((float4*)xrow)[tid] = ((const float4*)(query + (size_t)bq * DM))[tid];
  __syncthreads();
  const int j = tid;
  float acc = bias[j];
  const float4* wr = (const float4*)(W + (size_t)j * DM);
  #pragma unroll 8
  for (int c = 0; c < 64; ++c) {
    float4 w = wr[c];
    float4 x = ((const float4*)xrow)[c];
    acc += w.x * x.x + w.y * x.y + w.z * x.z + w.w * x.w;
  }
  acc *= SCALE2;
  const int h = j >> 5, d = j & 31;
  q_bf[(((size_t)(b * NH + h)) * QQ + qi) * HD + d] = f2bf(acc);
}

// ---------------------------------------------------------------------------
// Kernel 2: K/V projection GEMM, barrier-free, single-pass over A.
// BM=64 rows, all 512 output cols per block: waves 0-1 -> K, waves 2-3 -> V.
// K stored (b,h,key,d); V stored transposed (b,h,d,key). Unchanged from R4.
// ---------------------------------------------------------------------------
__global__ __launch_bounds__(256) void proj_kv_kernel(
    const float* __restrict__ kv, const u16* __restrict__ wbf,
    const float* __restrict__ bias, u16* __restrict__ k_bf,
    u16* __restrict__ v_t) {
  __shared__ u16 Tl[4][5120];
  const int rb = blockIdx.x;                 // 2048 blocks of 64 keys
  const size_t m0 = (size_t)rb * 64;
  const int tid = threadIdx.x, lane = tid & 63, wid = tid >> 6;
  const int lane15 = lane & 15, quad = lane >> 4;
  const int jw = wid * 128;                  // col base within 512

  f32x4 acc[4][8];
  #pragma unroll
  for (int mi = 0; mi < 4; ++mi)
    #pragma unroll
    for (int ni = 0; ni < 8; ++ni) acc[mi][ni] = (f32x4){0.f, 0.f, 0.f, 0.f};

  for (int ks = 0; ks < 8; ++ks) {
    bf16x8 afr[4];
    #pragma unroll
    for (int mi = 0; mi < 4; ++mi) {
      const float* ap = kv + (m0 + mi * 16 + lane15) * DM + ks * 32 + quad * 8;
      float4 a0 = ((const float4*)ap)[0];
      float4 a1 = ((const float4*)ap)[1];
      uint4 w;
      w.x = pack2rn(a0.x, a0.y); w.y = pack2rn(a0.z, a0.w);
      w.z = pack2rn(a1.x, a1.y); w.w = pack2rn(a1.z, a1.w);
      afr[mi] = __builtin_bit_cast(bf16x8, w);
    }
    #pragma unroll
    for (int ni = 0; ni < 8; ++ni) {
      bf16x8 bfr = __builtin_bit_cast(bf16x8,
          *(const uint4*)(wbf + (size_t)(jw + ni * 16 + lane15) * DM + ks * 32 + quad * 8));
      #pragma unroll
      for (int mi = 0; mi < 4; ++mi)
        acc[mi][ni] = __builtin_amdgcn_mfma_f32_16x16x32_bf16(afr[mi], bfr, acc[mi][ni], 0, 0, 0);
    }
  }

  u16* T = Tl[wid];
  const float* bptr = bias + 256 + jw;
  if (wid < 2) {
    #pragma unroll
    for (int p = 0; p < 2; ++p) {
      #pragma unroll
      for (int mm = 0; mm < 2; ++mm) {
        const int mi = p * 2 + mm;
        #pragma unroll
        for (int ni = 0; ni < 8; ++ni) {
          const float bv = bptr[ni * 16 + lane15];
          #pragma unroll
          for (int r = 0; r < 4; ++r)
            T[(mm * 16 + quad * 4 + r) * 136 + ni * 16 + lane15] =
                f2bf_ru(acc[mi][ni][r] + bv);
        }
      }
      #pragma unroll
      for (int it = 0; it < 8; ++it) {
        const int row = it * 4 + quad;          // 0..31
        const int c0 = lane15 * 8;              // 0..120
        uint4 val = *(const uint4*)&T[row * 136 + c0];
        const size_t m = m0 + p * 32 + row;
        const size_t b = m >> 14, key = m & 16383;
        const int col256 = jw + c0;             // 0..255 within K
        const int h = col256 >> 5, d = col256 & 31;
        *(uint4*)&k_bf[((b * NH + h) * HWK + key) * HD + d] = val;
      }
    }
  } else {
    const int jwv = jw - 256;                   // 0 or 128 within V
    #pragma unroll
    for (int p = 0; p < 2; ++p) {
      #pragma unroll
      for (int mm = 0; mm < 2; ++mm) {
        const int mi = p * 2 + mm;
        #pragma unroll
        for (int ni = 0; ni < 8; ++ni) {
          const float bv = bptr[ni * 16 + lane15];
          u32* dst = (u32*)&T[(ni * 16 + lane15) * 40 + mm * 16 + quad * 4];
          dst[0] = pack2rn(acc[mi][ni][0] + bv, acc[mi][ni][1] + bv);
          dst[1] = pack2rn(acc[mi][ni][2] + bv, acc[mi][ni][3] + bv);
        }
      }
      #pragma unroll
      for (int it = 0; it < 8; ++it) {
        const int col = it * 16 + (lane >> 2);  // 0..127
        const int koff = (lane & 3) * 8;        // 0..24
        uint4 val = *(const uint4*)&T[col * 40 + koff];
        const size_t m = m0 + p * 32 + koff;
        const size_t b = m >> 14, key = m & 16383;
        const int col256 = jwv + col;           // 0..255 within V
        const int h = col256 >> 5, d = col256 & 31;
        *(uint4*)&v_t[((b * NH + h) * HD + d) * HWK + key] = val;
      }
    }
  }
}

// ---------------------------------------------------------------------------
// Kernel 3: chunked attention, TRANSPOSED score path (no LDS in hot loop).
// R-new: WAVE-PRIVATE mask compression. Each wave ballot-compresses its OWN
// 256-key strip for all rows into its own padded LDS region (stride 9 words,
// bank-conflict-free), so no cross-wave exchange and no barrier between the
// mask phase and the MFMA main loop -> waves slide (BW phase of one wave
// overlaps compute of siblings). Rows >= QQ pre-zeroed (drops per-iter mask).
// s_setprio(1) around the MFMA loop: waves are now at different phases, so
// priority arbitration has something to do (T5, structure-conditional).
// ---------------------------------------------------------------------------
__global__ __launch_bounds__(256) void attn_kernel(
    const u16* __restrict__ q_bf, const u16* __restrict__ k_bf,
    const u16* __restrict__ v_t, const int* __restrict__ mask,
    float* __restrict__ l_p, u32* __restrict__ ctxp) {
  __shared__ u16 qlds[QP * 40];
  __shared__ u32 mb[4 * QP * 9];       // per-wave [QP][9] bitmap, stride 9 = conflict-free
  const int tid = threadIdx.x;
  const int lane = tid & 63, wid = tid >> 6;
  const int lane15 = lane & 15, quad = lane >> 4;
  const int bh = blockIdx.x >> 4, chunk = blockIdx.x & 15;

  for (int i = tid; i < QP * HD; i += 256) {
    const int row = i >> 5, d = i & 31;
    qlds[row * 40 + d] = (row < QQ) ? q_bf[((size_t)bh * QQ + row) * HD + d] : (u16)0;
  }
  __syncthreads();   // only for qlds; mask bitmap below is wave-private

  // wave-private ballot-compress: wave w covers keys [chunk*1024 + w*256, +256)
  u32* mbw = mb + wid * (QP * 9);
  {
    const int* mp_base = mask + (size_t)bh * QQ * HWK + chunk * 1024 + wid * 256;
    #pragma unroll 2
    for (int r = 0; r < QQ; ++r) {
      const int* mp = mp_base + (size_t)r * HWK;
      u32 myw = 0;
      #pragma unroll
      for (int g = 0; g < 4; ++g) {
        const u64 bl = __ballot(mp[g * 64 + lane] != 0);
        if (lane == 2 * g)     myw = (u32)bl;
        if (lane == 2 * g + 1) myw = (u32)(bl >> 32);
      }
      if (lane < 8) mbw[r * 9 + lane] = myw;
    }
    if (lane < 8) {
      #pragma unroll
      for (int r = QQ; r < QP; ++r) mbw[r * 9 + lane] = 0u;
    }
  }

  const int klocal_base = wid * 256;
  const int key_base = chunk * 1024 + klocal_base;
  const u16* kbase = k_bf + (size_t)bh * HWK * HD;
  const u16* vtb  = v_t  + (size_t)bh * HWK * HD;

  // cross-quad shuffle constants for the P^T relay
  const int sl_lo = lane15 + 32 * (quad & 1);
  const int sl_hi = sl_lo + 16;
  const u32 selperm = (quad & 2) ? 0x07060302u : 0x05040100u;  // hi : lo halves

  f32x4 acc[MT][2];
  float l_run[MT];
  #pragma unroll
  for (int mt = 0; mt < MT; ++mt) {
    acc[mt][0] = (f32x4){0.f, 0.f, 0.f, 0.f};
    acc[mt][1] = (f32x4){0.f, 0.f, 0.f, 0.f};
    l_run[mt] = 0.f;
  }

  __builtin_amdgcn_s_setprio(1);
  for (int kg = 0; kg < 8; ++kg) {
    const int key0 = key_base + kg * 32;
    bf16x8 kf0 = __builtin_bit_cast(bf16x8,
        *(const uint4*)(kbase + (size_t)(key0 + lane15) * HD + quad * 8));
    bf16x8 kf1 = __builtin_bit_cast(bf16x8,
        *(const uint4*)(kbase + (size_t)(key0 + 16 + lane15) * HD + quad * 8));
    bf16x8 vf0 = __builtin_bit_cast(bf16x8,
        *(const uint4*)(vtb + (size_t)lane15 * HWK + key0 + quad * 8));
    bf16x8 vf1 = __builtin_bit_cast(bf16x8,
        *(const uint4*)(vtb + (size_t)(lane15 + 16) * HWK + key0 + quad * 8));
    #pragma unroll
    for (int mt = 0; mt < MT; ++mt) {
      const int rowg = mt * 16 + lane15;              // this lane's q-row
      bf16x8 af = __builtin_bit_cast(bf16x8,
          *(const uint4*)&qlds[rowg * 40 + quad * 8]);
      const f32x4 zero = {0.f, 0.f, 0.f, 0.f};
      // S^T: m=key(quad*4+r), n=qrow(lane15)
      f32x4 s0 = __builtin_amdgcn_mfma_f32_16x16x32_bf16(kf0, af, zero, 0, 0, 0);
      f32x4 s1 = __builtin_amdgcn_mfma_f32_16x16x32_bf16(kf1, af, zero, 0, 0, 0);
      const u32 word = mbw[rowg * 9 + kg];            // rows >= QQ pre-zeroed
      u32 pk[4];
      float lsum = 0.f;
      #pragma unroll
      for (int r = 0; r < 4; ++r) {
        const int kl = quad * 4 + r;
        const float p0 = ((word >> kl) & 1u)        ? fast_exp2(s0[r]) : 0.f;
        const float p1 = ((word >> (kl + 16)) & 1u) ? fast_exp2(s1[r]) : 0.f;
        lsum += p0 + p1;
        pk[r] = pack2rn(p0, p1);   // lo = key kl, hi = key kl+16
      }
      l_run[mt] += lsum;
      // relay P^T into B-operand layout: lane needs keys 8*quad + j
      u32 wA0 = (u32)__shfl((int)pk[0], sl_lo);
      u32 wA1 = (u32)__shfl((int)pk[1], sl_lo);
      u32 wA2 = (u32)__shfl((int)pk[2], sl_lo);
      u32 wA3 = (u32)__shfl((int)pk[3], sl_lo);
      u32 wB0 = (u32)__shfl((int)pk[0], sl_hi);
      u32 wB1 = (u32)__shfl((int)pk[1], sl_hi);
      u32 wB2 = (u32)__shfl((int)pk[2], sl_hi);
      u32 wB3 = (u32)__shfl((int)pk[3], sl_hi);
      uint4 pw;
      pw.x = __builtin_amdgcn_perm(wA1, wA0, selperm);
      pw.y = __builtin_amdgcn_perm(wA3, wA2, selperm);
      pw.z = __builtin_amdgcn_perm(wB1, wB0, selperm);
      pw.w = __builtin_amdgcn_perm(wB3, wB2, selperm);
      bf16x8 pf = __builtin_bit_cast(bf16x8, pw);
      // ctx^T: m=dim, n=qrow
      acc[mt][0] = __builtin_amdgcn_mfma_f32_16x16x32_bf16(vf0, pf, acc[mt][0], 0, 0, 0);
      acc[mt][1] = __builtin_amdgcn_mfma_f32_16x16x32_bf16(vf1, pf, acc[mt][1], 0, 0, 0);
    }
  }
  __builtin_amdgcn_s_setprio(0);

  const int part = chunk * 4 + wid;
  #pragma unroll
  for (int mt = 0; mt < MT; ++mt) {
    const int row = mt * 16 + lane15;               // qrow (rows >= 100 junk, never read)
    float lr = l_run[mt];
    lr += __shfl_xor(lr, 16);
    lr += __shfl_xor(lr, 32);
    const size_t base = ((size_t)bh * QP + row) * NPART + part;
    if (quad == 0) l_p[base] = lr;
    // ctx^T: lane holds dims quad*4+r (acc0) and 16+quad*4+r (acc1), qrow=lane15
    uint2 lo2, hi2;
    lo2.x = pack2rn(acc[mt][0][0], acc[mt][0][1]);
    lo2.y = pack2rn(acc[mt][0][2], acc[mt][0][3]);
    hi2.x = pack2rn(acc[mt][1][0], acc[mt][1][1]);
    hi2.y = pack2rn(acc[mt][1][2], acc[mt][1][3]);
    *(uint2*)&ctxp[base * 16 + quad * 2]     = lo2;  // dims 4q..4q+3
    *(uint2*)&ctxp[base * 16 + 8 + quad * 2] = hi2;  // dims 16+4q..16+4q+3
  }
}

// ---------------------------------------------------------------------------
// Kernel 4: combine partials (bf16-packed ctx) + out-proj + residual + LN.
// ---------------------------------------------------------------------------
__global__ __launch_bounds__(256) void combine_kernel(
    const float* __restrict__ l_p, const u32* __restrict__ ctxp,
    const float* __restrict__ query, const float* __restrict__ Wo,
    const float* __restrict__ bo, const float* __restrict__ lnw,
    const float* __restrict__ lnb, float* __restrict__ out) {
  __shared__ float ctx_row[DM];
  __shared__ float red[8];
  const int bq = blockIdx.x;
  const int b = bq / QQ, qi = bq % QQ;
  const int tid = threadIdx.x, lane = tid & 63, wid = tid >> 6;

  for (int hh = 0; hh < 2; ++hh) {
    const int h = wid * 2 + hh;
    const size_t base = ((size_t)(b * NH + h) * QP + qi) * NPART;
    float lv = l_p[base + lane];
    #pragma unroll
    for (int o = 1; o < 64; o <<= 1) lv += __shfl_xor(lv, o);
    const float inv_l = 1.0f / lv;
    // lane = (part group pg, u32-pair c): dims 4c..4c+3
    const int c = lane & 7, pg = lane >> 3;
    const u32* cp = ctxp + base * 16 + c * 2;
    float s0 = 0.f, s1 = 0.f, s2 = 0.f, s3 = 0.f;
    for (int p = pg; p < NPART; p += 8) {
      uint2 u = *(const uint2*)(cp + (size_t)p * 16);
      s0 += bf_lo(u.x); s1 += bf_hi(u.x);
      s2 += bf_lo(u.y); s3 += bf_hi(u.y);
    }
    #pragma unroll
    for (int o = 8; o < 64; o <<= 1) {
      s0 += __shfl_xor(s0, o);
      s1 += __shfl_xor(s1, o);
      s2 += __shfl_xor(s2, o);
      s3 += __shfl_xor(s3, o);
    }
    if (pg == 0) {
      ctx_row[h * HD + c * 4]     = s0 * inv_l;
      ctx_row[h * HD + c * 4 + 1] = s1 * inv_l;
      ctx_row[h * HD + c * 4 + 2] = s2 * inv_l;
      ctx_row[h * HD + c * 4 + 3] = s3 * inv_l;
    }
  }
  __syncthreads();

  const int j = tid;
  float s = bo[j];
  const float4* wr = (const float4*)(Wo + (size_t)j * DM);
  #pragma unroll 8
  for (int c = 0; c < 64; ++c) {
    float4 wv = wr[c];
    float4 cx = ((const float4*)ctx_row)[c];
    s += wv.x * cx.x + wv.y * cx.y + wv.z * cx.z + wv.w * cx.w;
  }
  const float x = s + query[(size_t)bq * DM + j];

  float t = x;
  #pragma unroll
  for (int o = 1; o < 64; o <<= 1) t += __shfl_xor(t, o);
  if (lane == 0) red[wid] = t;
  __syncthreads();
  const float mu = (red[0] + red[1] + red[2] + red[3]) * (1.0f / DM);
  const float dx = x - mu;
  float t2 = dx * dx;
  #pragma unroll
  for (int o = 1; o < 64; o <<= 1) t2 += __shfl_xor(t2, o);
  if (lane == 0) red[4 + wid] = t2;
  __syncthreads();
  const float var = (red[4] + red[5] + red[6] + red[7]) * (1.0f / DM);
  out[(size_t)bq * DM + j] = dx * rsqrtf(var + 1e-5f) * lnw[j] + lnb[j];
}

// ---------------------------------------------------------------------------
extern "C" void kernel_launch(void* const* d_in, const int* in_sizes, int n_in,
                              void* d_out, int out_size, void* d_ws, size_t ws_size,
                              hipStream_t stream) {
  const float* query = (const float*)d_in[0];
  const float* kv    = (const float*)d_in[1];
  const int*   mask  = (const int*)d_in[2];
  const float* ipw   = (const float*)d_in[3];
  const float* ipb   = (const float*)d_in[4];
  const float* opw   = (const float*)d_in[5];
  const float* opb   = (const float*)d_in[6];
  const float* lnw   = (const float*)d_in[7];
  const float* lnb   = (const float*)d_in[8];
  float* out = (float*)d_out;

  char* ws = (char*)d_ws;
  // ws: k 64MiB | v_t 64MiB | q 0.5MiB | l_p 1.75MiB | ctxp 28.7MiB | wbf 0.25MiB
  u16*   k_bf  = (u16*)(ws);
  u16*   v_t   = (u16*)(ws + 67108864);
  u16*   q_bf  = (u16*)(ws + 134217728);
  float* l_p   = (float*)(ws + 134742016);
  u32*   ctxp  = (u32*)(ws + 136577024);
  u16*   wbf   = (u16*)(ws + 195297280);

  wconv_kernel  <<<128,          256, 0, stream>>>(ipw, wbf);
  proj_q_kernel <<<BB * QQ,      256, 0, stream>>>(query, ipw, ipb, q_bf);
  proj_kv_kernel<<<2048,         256, 0, stream>>>(kv, wbf, ipb, k_bf, v_t);
  attn_kernel   <<<BB * NH * 16, 256, 0, stream>>>(q_bf, k_bf, v_t, mask, l_p, ctxp);
  combine_kernel<<<BB * QQ,      256, 0, stream>>>(l_p, ctxp, query, opw, opb, lnw, lnb, out);
}

// Round 2
// 870.118 us; speedup vs baseline: 1.0476x; 1.0476x over previous
//
#include <hip/hip_runtime.h>
#include <stdint.h>

// Problem constants
#define BB   8
#define NH   8
#define QQ   100
#define HWK  16384
#define DM   256
#define HD   32
#define QP   112      // Q padded to 7 * 16
#define MT   7        // m-tiles of 16 rows
#define NPART 64      // key partials per (b,h): 16 chunks * 4 waves
// 1/sqrt(32) * log2(e)  (exp(x) == exp2(x*log2e), folded into q-scale)
#define SCALE2 0.2550602534365564f

typedef short bf16x8 __attribute__((ext_vector_type(8)));
typedef float f32x4  __attribute__((ext_vector_type(4)));
typedef unsigned int u32x4 __attribute__((ext_vector_type(4)));
typedef unsigned short u16;
typedef unsigned int   u32;
typedef unsigned long long u64;

__device__ __forceinline__ u16 f2bf(float f) {          // RNE
  u32 u = __builtin_bit_cast(u32, f);
  u += 0x7fffu + ((u >> 16) & 1u);
  return (u16)(u >> 16);
}
__device__ __forceinline__ u16 f2bf_ru(float f) {       // round-half-up (2 VALU)
  return (u16)((__builtin_bit_cast(u32, f) + 0x8000u) >> 16);
}
// pack two fp32 -> bf16x2 (round-half-up), 3 VALU via v_perm
__device__ __forceinline__ u32 pack2rn(float lo, float hi) {
  u32 a = __builtin_bit_cast(u32, lo) + 0x8000u;
  u32 b = __builtin_bit_cast(u32, hi) + 0x8000u;
  return __builtin_amdgcn_perm(b, a, 0x07060302u);
}
__device__ __forceinline__ float bf_lo(u32 u) {
  return __builtin_bit_cast(float, u << 16);
}
__device__ __forceinline__ float bf_hi(u32 u) {
  return __builtin_bit_cast(float, u & 0xffff0000u);
}
__device__ __forceinline__ float fast_exp2(float x) {
#if __has_builtin(__builtin_amdgcn_exp2f)
  return __builtin_amdgcn_exp2f(x);
#else
  return exp2f(x);
#endif
}

// ---------------------------------------------------------------------------
// Kernel 0: convert W_kv (in_proj rows 256..767) fp32 -> bf16, row-major.
// ---------------------------------------------------------------------------
__global__ __launch_bounds__(256) void wconv_kernel(
    const float* __restrict__ W, u16* __restrict__ wbf) {
  const int i = (blockIdx.x * 256 + threadIdx.x) * 4;   // 131072 elems
  const float4 w = *(const float4*)(W + 256 * DM + i);
  u32* dst = (u32*)(wbf + i);
  dst[0] = pack2rn(w.x, w.y);
  dst[1] = pack2rn(w.z, w.w);
}

// ---------------------------------------------------------------------------
// Kernel 1: q projection (scale*log2e folded in).  q_bf layout (b,h,qi,d).
// ---------------------------------------------------------------------------
__global__ __launch_bounds__(256) void proj_q_kernel(
    const float* __restrict__ query, const float* __restrict__ W,
    const float* __restrict__ bias, u16* __restrict__ q_bf) {
  __shared__ float xrow[DM];
  const int bq = blockIdx.x;
  const int b = bq / QQ, qi = bq % QQ;
  const int tid = threadIdx.x;
  if (tid < 64)
    ((float4*)xrow)[tid] = ((const float4*)(query + (size_t)bq * DM))[tid];
  __syncthreads();
  const int j = tid;
  float acc = bias[j];
  const float4* wr = (const float4*)(W + (size_t)j * DM);
  #pragma unroll 8
  for (int c = 0; c < 64; ++c) {
    float4 w = wr[c];
    float4 x = ((const float4*)xrow)[c];
    acc += w.x * x.x + w.y * x.y + w.z * x.z + w.w * x.w;
  }
  acc *= SCALE2;
  const int h = j >> 5, d = j & 31;
  q_bf[(((size_t)(b * NH + h)) * QQ + qi) * HD + d] = f2bf(acc);
}

// ---------------------------------------------------------------------------
// Kernel 2: K/V projection GEMM, barrier-free, single-pass over A.
// BM=64 rows, all 512 output cols per block: waves 0-1 -> K, waves 2-3 -> V.
// K stored (b,h,key,d); V stored transposed (b,h,d,key). Unchanged from R4.
// ---------------------------------------------------------------------------
__global__ __launch_bounds__(256) void proj_kv_kernel(
    const float* __restrict__ kv, const u16* __restrict__ wbf,
    const float* __restrict__ bias, u16* __restrict__ k_bf,
    u16* __restrict__ v_t) {
  __shared__ u16 Tl[4][5120];
  const int rb = blockIdx.x;                 // 2048 blocks of 64 keys
  const size_t m0 = (size_t)rb * 64;
  const int tid = threadIdx.x, lane = tid & 63, wid = tid >> 6;
  const int lane15 = lane & 15, quad = lane >> 4;
  const int jw = wid * 128;                  // col base within 512

  f32x4 acc[4][8];
  #pragma unroll
  for (int mi = 0; mi < 4; ++mi)
    #pragma unroll
    for (int ni = 0; ni < 8; ++ni) acc[mi][ni] = (f32x4){0.f, 0.f, 0.f, 0.f};

  for (int ks = 0; ks < 8; ++ks) {
    bf16x8 afr[4];
    #pragma unroll
    for (int mi = 0; mi < 4; ++mi) {
      const float* ap = kv + (m0 + mi * 16 + lane15) * DM + ks * 32 + quad * 8;
      float4 a0 = ((const float4*)ap)[0];
      float4 a1 = ((const float4*)ap)[1];
      uint4 w;
      w.x = pack2rn(a0.x, a0.y); w.y = pack2rn(a0.z, a0.w);
      w.z = pack2rn(a1.x, a1.y); w.w = pack2rn(a1.z, a1.w);
      afr[mi] = __builtin_bit_cast(bf16x8, w);
    }
    #pragma unroll
    for (int ni = 0; ni < 8; ++ni) {
      bf16x8 bfr = __builtin_bit_cast(bf16x8,
          *(const uint4*)(wbf + (size_t)(jw + ni * 16 + lane15) * DM + ks * 32 + quad * 8));
      #pragma unroll
      for (int mi = 0; mi < 4; ++mi)
        acc[mi][ni] = __builtin_amdgcn_mfma_f32_16x16x32_bf16(afr[mi], bfr, acc[mi][ni], 0, 0, 0);
    }
  }

  u16* T = Tl[wid];
  const float* bptr = bias + 256 + jw;
  if (wid < 2) {
    #pragma unroll
    for (int p = 0; p < 2; ++p) {
      #pragma unroll
      for (int mm = 0; mm < 2; ++mm) {
        const int mi = p * 2 + mm;
        #pragma unroll
        for (int ni = 0; ni < 8; ++ni) {
          const float bv = bptr[ni * 16 + lane15];
          #pragma unroll
          for (int r = 0; r < 4; ++r)
            T[(mm * 16 + quad * 4 + r) * 136 + ni * 16 + lane15] =
                f2bf_ru(acc[mi][ni][r] + bv);
        }
      }
      #pragma unroll
      for (int it = 0; it < 8; ++it) {
        const int row = it * 4 + quad;          // 0..31
        const int c0 = lane15 * 8;              // 0..120
        uint4 val = *(const uint4*)&T[row * 136 + c0];
        const size_t m = m0 + p * 32 + row;
        const size_t b = m >> 14, key = m & 16383;
        const int col256 = jw + c0;             // 0..255 within K
        const int h = col256 >> 5, d = col256 & 31;
        *(uint4*)&k_bf[((b * NH + h) * HWK + key) * HD + d] = val;
      }
    }
  } else {
    const int jwv = jw - 256;                   // 0 or 128 within V
    #pragma unroll
    for (int p = 0; p < 2; ++p) {
      #pragma unroll
      for (int mm = 0; mm < 2; ++mm) {
        const int mi = p * 2 + mm;
        #pragma unroll
        for (int ni = 0; ni < 8; ++ni) {
          const float bv = bptr[ni * 16 + lane15];
          u32* dst = (u32*)&T[(ni * 16 + lane15) * 40 + mm * 16 + quad * 4];
          dst[0] = pack2rn(acc[mi][ni][0] + bv, acc[mi][ni][1] + bv);
          dst[1] = pack2rn(acc[mi][ni][2] + bv, acc[mi][ni][3] + bv);
        }
      }
      #pragma unroll
      for (int it = 0; it < 8; ++it) {
        const int col = it * 16 + (lane >> 2);  // 0..127
        const int koff = (lane & 3) * 8;        // 0..24
        uint4 val = *(const uint4*)&T[col * 40 + koff];
        const size_t m = m0 + p * 32 + koff;
        const size_t b = m >> 14, key = m & 16383;
        const int col256 = jwv + col;           // 0..255 within V
        const int h = col256 >> 5, d = col256 & 31;
        *(uint4*)&v_t[((b * NH + h) * HD + d) * HWK + key] = val;
      }
    }
  }
}

// ---------------------------------------------------------------------------
// Kernel 3: chunked attention (R0 structure: cross-wave mask rows + barrier,
// no setprio). NEW mask path: uint4 loads (4 keys/lane, 256 keys per load
// inst) + interleaved ballot order -- bit l of ballot_j = key 4l+j. No
// repacking: for key slot s=4*quad+r in group kg the bit lives in word j=r,
// half h=(kg>=4), bit 8*(kg&3)+quad (the +16 key at +4, same word). Bitmap
// layout mb[row][quarter q][h][j], row stride 52 dwords (16B-aligned b128
// reads, 2-way conflict only = free). Same extraction VALU cost as before.
// ---------------------------------------------------------------------------
__global__ __launch_bounds__(256) void attn_kernel(
    const u16* __restrict__ q_bf, const u16* __restrict__ k_bf,
    const u16* __restrict__ v_t, const int* __restrict__ mask,
    float* __restrict__ l_p, u32* __restrict__ ctxp) {
  __shared__ u16 qlds[QP * 40];
  __shared__ u32 mb[QP * 52];          // [row][q:4][h:2][j:4], stride 52
  const int tid = threadIdx.x;
  const int lane = tid & 63, wid = tid >> 6;
  const int lane15 = lane & 15, quad = lane >> 4;
  const int bh = blockIdx.x >> 4, chunk = blockIdx.x & 15;

  for (int i = tid; i < QP * HD; i += 256) {
    const int row = i >> 5, d = i & 31;
    qlds[row * 40 + d] = (row < QQ) ? q_bf[((size_t)bh * QQ + row) * HD + d] : (u16)0;
  }
  // zero pad rows 100..111 (12 rows * 52 words)
  for (int i = tid; i < 12 * 52; i += 256) mb[QQ * 52 + i] = 0u;

  // mask compress: wave w -> rows [25w, 25w+25), all 4 quarters of the chunk.
  // Per row: 4 x int4 loads (64B/lane in flight, same as R0's 16x4B) +
  // 16 ballots, vs R0's 16 loads. 4x fewer VMEM issue slots.
  {
    const int* mp_base = mask + (size_t)bh * QQ * HWK + chunk * 1024;
    for (int rr = 0; rr < 25; ++rr) {
      const int row = wid * 25 + rr;
      const int* mp = mp_base + (size_t)row * HWK;
      int4 v[4];
      #pragma unroll
      for (int q = 0; q < 4; ++q) v[q] = ((const int4*)(mp + q * 256))[lane];
      #pragma unroll
      for (int q = 0; q < 4; ++q) {
        const u64 b0 = __ballot(v[q].x != 0);
        const u64 b1 = __ballot(v[q].y != 0);
        const u64 b2 = __ballot(v[q].z != 0);
        const u64 b3 = __ballot(v[q].w != 0);
        if (lane < 8) {
          const int j = lane >> 1;
          const u64 bj = (j == 0) ? b0 : (j == 1) ? b1 : (j == 2) ? b2 : b3;
          mb[row * 52 + q * 12 + (lane & 1) * 4 + j] =
              (lane & 1) ? (u32)(bj >> 32) : (u32)bj;
        }
      }
    }
  }
  __syncthreads();

  const int klocal_base = wid * 256;
  const int key_base = chunk * 1024 + klocal_base;
  const u16* kbase = k_bf + (size_t)bh * HWK * HD;
  const u16* vtb  = v_t  + (size_t)bh * HWK * HD;

  // cross-quad shuffle constants for the P^T relay
  const int sl_lo = lane15 + 32 * (quad & 1);
  const int sl_hi = sl_lo + 16;
  const u32 selperm = (quad & 2) ? 0x07060302u : 0x05040100u;  // hi : lo halves

  f32x4 acc[MT][2];
  float l_run[MT];
  #pragma unroll
  for (int mt = 0; mt < MT; ++mt) {
    acc[mt][0] = (f32x4){0.f, 0.f, 0.f, 0.f};
    acc[mt][1] = (f32x4){0.f, 0.f, 0.f, 0.f};
    l_run[mt] = 0.f;
  }

  for (int kg = 0; kg < 8; ++kg) {
    const int key0 = key_base + kg * 32;
    const int mwoff = wid * 12 + ((kg & 4) ? 4 : 0);  // quarter wid, half kg>=4
    const int sh = ((kg & 3) << 3) + quad;            // bit base for this kg
    bf16x8 kf0 = __builtin_bit_cast(bf16x8,
        *(const uint4*)(kbase + (size_t)(key0 + lane15) * HD + quad * 8));
    bf16x8 kf1 = __builtin_bit_cast(bf16x8,
        *(const uint4*)(kbase + (size_t)(key0 + 16 + lane15) * HD + quad * 8));
    bf16x8 vf0 = __builtin_bit_cast(bf16x8,
        *(const uint4*)(vtb + (size_t)lane15 * HWK + key0 + quad * 8));
    bf16x8 vf1 = __builtin_bit_cast(bf16x8,
        *(const uint4*)(vtb + (size_t)(lane15 + 16) * HWK + key0 + quad * 8));
    #pragma unroll
    for (int mt = 0; mt < MT; ++mt) {
      const int rowg = mt * 16 + lane15;              // this lane's q-row
      bf16x8 af = __builtin_bit_cast(bf16x8,
          *(const uint4*)&qlds[rowg * 40 + quad * 8]);
      u32x4 mw = *(const u32x4*)&mb[rowg * 52 + mwoff]; // words j=0..3
      const f32x4 zero = {0.f, 0.f, 0.f, 0.f};
      // S^T: m=key(quad*4+r), n=qrow(lane15)
      f32x4 s0 = __builtin_amdgcn_mfma_f32_16x16x32_bf16(kf0, af, zero, 0, 0, 0);
      f32x4 s1 = __builtin_amdgcn_mfma_f32_16x16x32_bf16(kf1, af, zero, 0, 0, 0);
      u32 pk[4];
      float lsum = 0.f;
      #pragma unroll
      for (int r = 0; r < 4; ++r) {
        // key slot 4*quad+r -> word j=r, bit sh; slot +16 -> bit sh+4
        const float p0 = ((mw[r] >> sh) & 1u)       ? fast_exp2(s0[r]) : 0.f;
        const float p1 = ((mw[r] >> (sh + 4)) & 1u) ? fast_exp2(s1[r]) : 0.f;
        lsum += p0 + p1;
        pk[r] = pack2rn(p0, p1);   // lo = key kl, hi = key kl+16
      }
      l_run[mt] += lsum;
      // relay P^T into B-operand layout: lane needs keys 8*quad + j
      u32 wA0 = (u32)__shfl((int)pk[0], sl_lo);
      u32 wA1 = (u32)__shfl((int)pk[1], sl_lo);
      u32 wA2 = (u32)__shfl((int)pk[2], sl_lo);
      u32 wA3 = (u32)__shfl((int)pk[3], sl_lo);
      u32 wB0 = (u32)__shfl((int)pk[0], sl_hi);
      u32 wB1 = (u32)__shfl((int)pk[1], sl_hi);
      u32 wB2 = (u32)__shfl((int)pk[2], sl_hi);
      u32 wB3 = (u32)__shfl((int)pk[3], sl_hi);
      uint4 pw;
      pw.x = __builtin_amdgcn_perm(wA1, wA0, selperm);
      pw.y = __builtin_amdgcn_perm(wA3, wA2, selperm);
      pw.z = __builtin_amdgcn_perm(wB1, wB0, selperm);
      pw.w = __builtin_amdgcn_perm(wB3, wB2, selperm);
      bf16x8 pf = __builtin_bit_cast(bf16x8, pw);
      // ctx^T: m=dim, n=qrow
      acc[mt][0] = __builtin_amdgcn_mfma_f32_16x16x32_bf16(vf0, pf, acc[mt][0], 0, 0, 0);
      acc[mt][1] = __builtin_amdgcn_mfma_f32_16x16x32_bf16(vf1, pf, acc[mt][1], 0, 0, 0);
    }
  }

  const int part = chunk * 4 + wid;
  #pragma unroll
  for (int mt = 0; mt < MT; ++mt) {
    const int row = mt * 16 + lane15;               // qrow (rows >= 100 junk, never read)
    float lr = l_run[mt];
    lr += __shfl_xor(lr, 16);
    lr += __shfl_xor(lr, 32);
    const size_t base = ((size_t)bh * QP + row) * NPART + part;
    if (quad == 0) l_p[base] = lr;
    // ctx^T: lane holds dims quad*4+r (acc0) and 16+quad*4+r (acc1), qrow=lane15
    uint2 lo2, hi2;
    lo2.x = pack2rn(acc[mt][0][0], acc[mt][0][1]);
    lo2.y = pack2rn(acc[mt][0][2], acc[mt][0][3]);
    hi2.x = pack2rn(acc[mt][1][0], acc[mt][1][1]);
    hi2.y = pack2rn(acc[mt][1][2], acc[mt][1][3]);
    *(uint2*)&ctxp[base * 16 + quad * 2]     = lo2;  // dims 4q..4q+3
    *(uint2*)&ctxp[base * 16 + 8 + quad * 2] = hi2;  // dims 16+4q..16+4q+3
  }
}

// ---------------------------------------------------------------------------
// Kernel 4: combine partials (bf16-packed ctx) + out-proj + residual + LN.
// ---------------------------------------------------------------------------
__global__ __launch_bounds__(256) void combine_kernel(
    const float* __restrict__ l_p, const u32* __restrict__ ctxp,
    const float* __restrict__ query, const float* __restrict__ Wo,
    const float* __restrict__ bo, const float* __restrict__ lnw,
    const float* __restrict__ lnb, float* __restrict__ out) {
  __shared__ float ctx_row[DM];
  __shared__ float red[8];
  const int bq = blockIdx.x;
  const int b = bq / QQ, qi = bq % QQ;
  const int tid = threadIdx.x, lane = tid & 63, wid = tid >> 6;

  for (int hh = 0; hh < 2; ++hh) {
    const int h = wid * 2 + hh;
    const size_t base = ((size_t)(b * NH + h) * QP + qi) * NPART;
    float lv = l_p[base + lane];
    #pragma unroll
    for (int o = 1; o < 64; o <<= 1) lv += __shfl_xor(lv, o);
    const float inv_l = 1.0f / lv;
    // lane = (part group pg, u32-pair c): dims 4c..4c+3
    const int c = lane & 7, pg = lane >> 3;
    const u32* cp = ctxp + base * 16 + c * 2;
    float s0 = 0.f, s1 = 0.f, s2 = 0.f, s3 = 0.f;
    for (int p = pg; p < NPART; p += 8) {
      uint2 u = *(const uint2*)(cp + (size_t)p * 16);
      s0 += bf_lo(u.x); s1 += bf_hi(u.x);
      s2 += bf_lo(u.y); s3 += bf_hi(u.y);
    }
    #pragma unroll
    for (int o = 8; o < 64; o <<= 1) {
      s0 += __shfl_xor(s0, o);
      s1 += __shfl_xor(s1, o);
      s2 += __shfl_xor(s2, o);
      s3 += __shfl_xor(s3, o);
    }
    if (pg == 0) {
      ctx_row[h * HD + c * 4]     = s0 * inv_l;
      ctx_row[h * HD + c * 4 + 1] = s1 * inv_l;
      ctx_row[h * HD + c * 4 + 2] = s2 * inv_l;
      ctx_row[h * HD + c * 4 + 3] = s3 * inv_l;
    }
  }
  __syncthreads();

  const int j = tid;
  float s = bo[j];
  const float4* wr = (const float4*)(Wo + (size_t)j * DM);
  #pragma unroll 8
  for (int c = 0; c < 64; ++c) {
    float4 wv = wr[c];
    float4 cx = ((const float4*)ctx_row)[c];
    s += wv.x * cx.x + wv.y * cx.y + wv.z * cx.z + wv.w * cx.w;
  }
  const float x = s + query[(size_t)bq * DM + j];

  float t = x;
  #pragma unroll
  for (int o = 1; o < 64; o <<= 1) t += __shfl_xor(t, o);
  if (lane == 0) red[wid] = t;
  __syncthreads();
  const float mu = (red[0] + red[1] + red[2] + red[3]) * (1.0f / DM);
  const float dx = x - mu;
  float t2 = dx * dx;
  #pragma unroll
  for (int o = 1; o < 64; o <<= 1) t2 += __shfl_xor(t2, o);
  if (lane == 0) red[4 + wid] = t2;
  __syncthreads();
  const float var = (red[4] + red[5] + red[6] + red[7]) * (1.0f / DM);
  out[(size_t)bq * DM + j] = dx * rsqrtf(var + 1e-5f) * lnw[j] + lnb[j];
}

// ---------------------------------------------------------------------------
extern "C" void kernel_launch(void* const* d_in, const int* in_sizes, int n_in,
                              void* d_out, int out_size, void* d_ws, size_t ws_size,
                              hipStream_t stream) {
  const float* query = (const float*)d_in[0];
  const float* kv    = (const float*)d_in[1];
  const int*   mask  = (const int*)d_in[2];
  const float* ipw   = (const float*)d_in[3];
  const float* ipb   = (const float*)d_in[4];
  const float* opw   = (const float*)d_in[5];
  const float* opb   = (const float*)d_in[6];
  const float* lnw   = (const float*)d_in[7];
  const float* lnb   = (const float*)d_in[8];
  float* out = (float*)d_out;

  char* ws = (char*)d_ws;
  // ws: k 64MiB | v_t 64MiB | q 0.5MiB | l_p 1.75MiB | ctxp 28.7MiB | wbf 0.25MiB
  u16*   k_bf  = (u16*)(ws);
  u16*   v_t   = (u16*)(ws + 67108864);
  u16*   q_bf  = (u16*)(ws + 134217728);
  float* l_p   = (float*)(ws + 134742016);
  u32*   ctxp  = (u32*)(ws + 136577024);
  u16*   wbf   = (u16*)(ws + 195297280);

  wconv_kernel  <<<128,          256, 0, stream>>>(ipw, wbf);
  proj_q_kernel <<<BB * QQ,      256, 0, stream>>>(query, ipw, ipb, q_bf);
  proj_kv_kernel<<<2048,         256, 0, stream>>>(kv, wbf, ipb, k_bf, v_t);
  attn_kernel   <<<BB * NH * 16, 256, 0, stream>>>(q_bf, k_bf, v_t, mask, l_p, ctxp);
  combine_kernel<<<BB * QQ,      256, 0, stream>>>(l_p, ctxp, query, opw, opb, lnw, lnb, out);
}